// Round 1
// baseline (455.428 us; speedup 1.0000x reference)
//
#include <hip/hip_runtime.h>
#include <cfloat>

#define PIXB 1024
static const size_t OFF_Z = 6291456;   // recon = 32*3*256*256
static const size_t OFF_E = 23068672;  // OFF_Z + 32*512*32*32
static const size_t OFF_A = 39845888;  // OFF_E + 32*512*32*32

// ---------------- encode: z_e = conv(x) + b, as GEMM 512x192 @ 192x32768 ----
__global__ __launch_bounds__(256) void k_encode(const float* __restrict__ x,
                                                const float* __restrict__ ew,
                                                const float* __restrict__ eb,
                                                float* __restrict__ out) {
  __shared__ __align__(16) float Ps[16][68];
  __shared__ __align__(16) float Ws[16][68];
  const int n0 = blockIdx.x * 64;
  const int b = n0 / PIXB;
  const int pixbase = n0 % PIXB;
  const int i0 = pixbase >> 5;
  const int c0 = blockIdx.y * 64;
  const int t = threadIdx.x;
  const int tx = t & 15, ty = t >> 4;
  float acc[4][4];
#pragma unroll
  for (int m = 0; m < 4; ++m)
#pragma unroll
    for (int p = 0; p < 4; ++p) acc[m][p] = 0.f;

  const int jj = t >> 3, kjj = t & 7;
  for (int kc = 0; kc < 12; ++kc) {
    const int ci = kc >> 2, kip = kc & 3;
#pragma unroll
    for (int rr = 0; rr < 4; ++rr) {
      const int di = rr >> 1, dki = rr & 1;
      const int row = (i0 + di) * 8 + kip * 2 + dki;
      const float v = x[(((size_t)b * 3 + ci) * 256 + row) * 256 + t];
      Ps[dki * 8 + kjj][di * 32 + jj] = v;
    }
    const int k0 = kc * 16;
#pragma unroll
    for (int ii = 0; ii < 4; ++ii) {
      const int idx = t + ii * 256;
      const int cc = idx >> 4, kk = idx & 15;
      Ws[kk][cc] = ew[(size_t)(c0 + cc) * 192 + k0 + kk];
    }
    __syncthreads();
#pragma unroll
    for (int kk = 0; kk < 16; ++kk) {
      const float4 av = *reinterpret_cast<const float4*>(&Ws[kk][ty * 4]);
      const float4 bv = *reinterpret_cast<const float4*>(&Ps[kk][tx * 4]);
      const float a[4] = {av.x, av.y, av.z, av.w};
      const float bb[4] = {bv.x, bv.y, bv.z, bv.w};
#pragma unroll
      for (int m = 0; m < 4; ++m)
#pragma unroll
        for (int p = 0; p < 4; ++p) acc[m][p] = fmaf(a[m], bb[p], acc[m][p]);
    }
    __syncthreads();
  }
#pragma unroll
  for (int m = 0; m < 4; ++m) {
    const int c = c0 + ty * 4 + m;
    const float bias = eb[c];
    float4 v;
    v.x = acc[m][0] + bias; v.y = acc[m][1] + bias;
    v.z = acc[m][2] + bias; v.w = acc[m][3] + bias;
    *reinterpret_cast<float4*>(&out[OFF_Z + ((size_t)b * 512 + c) * 1024 + pixbase + tx * 4]) = v;
  }
}

// ---------------- norms: z2[n] = sum_d z^2, w2[k] = sum_d W^2 ----------------
__global__ __launch_bounds__(256) void k_norms(const float* __restrict__ Wc,
                                               const float* __restrict__ outz,
                                               float* __restrict__ z2,
                                               float* __restrict__ w2) {
  const int t = threadIdx.x;
  if (blockIdx.x < 128) {
    const int n = blockIdx.x * 256 + t;
    const int b = n / PIXB, pix = n % PIXB;
    const float* zp = outz + OFF_Z + (size_t)b * 512 * 1024 + pix;
    float acc = 0.f;
    for (int d = 0; d < 512; ++d) { const float v = zp[(size_t)d * 1024]; acc = fmaf(v, v, acc); }
    z2[n] = acc;
  } else {
    const int k = (blockIdx.x - 128) * 256 + t;
    float acc = 0.f;
    for (int d = 0; d < 512; ++d) { const float v = Wc[(size_t)d * 512 + k]; acc = fmaf(v, v, acc); }
    w2[k] = acc;
  }
}

// -------- distance + argmin + gather: per block 32 pixels, all 512 codes ----
__global__ __launch_bounds__(256) void k_dist(const float* __restrict__ Wc,
                                              const float* __restrict__ z2ws,
                                              const float* __restrict__ w2ws,
                                              float* out) {
  __shared__ __align__(16) float Zs[32][36];
  __shared__ __align__(16) float Ws2[32][260];
  __shared__ float rv[32][33];
  __shared__ int   ri[32][33];
  __shared__ int   fin[32];
  const int n0 = blockIdx.x * 32;
  const int b = n0 / PIXB, pixbase = n0 % PIXB;
  const int t = threadIdx.x;
  const int tx = t & 7, ty = t >> 3;
  float bestv[4]; int besti[4]; float z2r[4];
#pragma unroll
  for (int p = 0; p < 4; ++p) {
    bestv[p] = FLT_MAX; besti[p] = 0x7fffffff;
    z2r[p] = z2ws[n0 + tx * 4 + p];
  }
  for (int cp = 0; cp < 2; ++cp) {
    const int cbase = cp * 256;
    float acc[4][8];
#pragma unroll
    for (int p = 0; p < 4; ++p)
#pragma unroll
      for (int c = 0; c < 8; ++c) acc[p][c] = 0.f;
    for (int dc = 0; dc < 16; ++dc) {
      {
        const int dd = t >> 3, p4 = t & 7;
        *reinterpret_cast<float4*>(&Zs[dd][p4 * 4]) =
          *reinterpret_cast<const float4*>(&out[OFF_Z + ((size_t)b * 512 + dc * 32 + dd) * 1024 + pixbase + p4 * 4]);
      }
#pragma unroll
      for (int ii = 0; ii < 8; ++ii) {
        const int id = t + ii * 256;
        const int dd = id >> 6, c4 = id & 63;
        *reinterpret_cast<float4*>(&Ws2[dd][c4 * 4]) =
          *reinterpret_cast<const float4*>(&Wc[(size_t)(dc * 32 + dd) * 512 + cbase + c4 * 4]);
      }
      __syncthreads();
#pragma unroll
      for (int dd = 0; dd < 32; ++dd) {
        const float4 zv = *reinterpret_cast<const float4*>(&Zs[dd][tx * 4]);
        const float4 wa = *reinterpret_cast<const float4*>(&Ws2[dd][ty * 8]);
        const float4 wb = *reinterpret_cast<const float4*>(&Ws2[dd][ty * 8 + 4]);
        const float z[4] = {zv.x, zv.y, zv.z, zv.w};
        const float w[8] = {wa.x, wa.y, wa.z, wa.w, wb.x, wb.y, wb.z, wb.w};
#pragma unroll
        for (int p = 0; p < 4; ++p)
#pragma unroll
          for (int c = 0; c < 8; ++c) acc[p][c] = fmaf(z[p], w[c], acc[p][c]);
      }
      __syncthreads();
    }
#pragma unroll
    for (int c = 0; c < 8; ++c) {
      const int code = cbase + ty * 8 + c;
      const float w2v = w2ws[code];
#pragma unroll
      for (int p = 0; p < 4; ++p) {
        const float s = z2r[p] - 2.0f * acc[p][c];   // matches ref rounding (2*zw exact)
        const float d2v = s + w2v;
        if (d2v < bestv[p] || (d2v == bestv[p] && code < besti[p])) { bestv[p] = d2v; besti[p] = code; }
      }
    }
  }
#pragma unroll
  for (int p = 0; p < 4; ++p) { rv[ty][tx * 4 + p] = bestv[p]; ri[ty][tx * 4 + p] = besti[p]; }
  __syncthreads();
  if (t < 32) {
    float bv = rv[0][t]; int bi = ri[0][t];
    for (int y = 1; y < 32; ++y) {
      const float v = rv[y][t]; const int i2 = ri[y][t];
      if (v < bv || (v == bv && i2 < bi)) { bv = v; bi = i2; }
    }
    out[OFF_A + n0 + t] = (float)bi;
    fin[t] = bi;
  }
  __syncthreads();
  const int pix = t & 31, d0g = t >> 5;
  const int kidx = fin[pix];
  for (int d = d0g; d < 512; d += 8)
    out[OFF_E + ((size_t)b * 512 + d) * 1024 + pixbase + pix] = Wc[(size_t)d * 512 + kidx];
}

// ---------------- decode: conv_transpose (kernel spatially FLIPPED) ---------
__global__ __launch_bounds__(256) void k_decode(const float* __restrict__ dw,
                                                const float* __restrict__ db,
                                                float* out) {
  __shared__ __align__(16) float Qs[32][132];
  __shared__ __align__(16) float Ws3[32][68];
  const int n0 = blockIdx.x * 128;
  const int b = n0 / PIXB, pixbase = n0 % PIXB;
  const int mt = blockIdx.y;
  const int t = threadIdx.x;
  const int pg = t & 31, ck = t >> 5;
  float acc[4][8];
#pragma unroll
  for (int p = 0; p < 4; ++p)
#pragma unroll
    for (int k = 0; k < 8; ++k) acc[p][k] = 0.f;
  for (int dc = 0; dc < 16; ++dc) {
#pragma unroll
    for (int ii = 0; ii < 4; ++ii) {
      const int id = t + ii * 256;
      const int dd = id >> 5, p4 = id & 31;
      *reinterpret_cast<float4*>(&Qs[dd][p4 * 4]) =
        *reinterpret_cast<const float4*>(&out[OFF_E + ((size_t)b * 512 + dc * 32 + dd) * 1024 + pixbase + p4 * 4]);
    }
#pragma unroll
    for (int ii = 0; ii < 2; ++ii) {
      const int id = t + ii * 256;
      const int dd = id >> 4, m4 = id & 15;
      *reinterpret_cast<float4*>(&Ws3[dd][m4 * 4]) =
        *reinterpret_cast<const float4*>(&dw[(size_t)(dc * 32 + dd) * 192 + mt * 64 + m4 * 4]);
    }
    __syncthreads();
#pragma unroll
    for (int dd = 0; dd < 32; ++dd) {
      const float4 qv = *reinterpret_cast<const float4*>(&Qs[dd][pg * 4]);
      const float4 wa = *reinterpret_cast<const float4*>(&Ws3[dd][ck * 8]);
      const float4 wb = *reinterpret_cast<const float4*>(&Ws3[dd][ck * 8 + 4]);
      const float q[4] = {qv.x, qv.y, qv.z, qv.w};
      const float w[8] = {wa.x, wa.y, wa.z, wa.w, wb.x, wb.y, wb.z, wb.w};
#pragma unroll
      for (int p = 0; p < 4; ++p)
#pragma unroll
        for (int k = 0; k < 8; ++k) acc[p][k] = fmaf(q[p], w[k], acc[p][k]);
    }
    __syncthreads();
  }
  const int ckg = mt * 8 + ck;
  const int c = ckg >> 3, ki = ckg & 7;
  const float bias = db[c];
#pragma unroll
  for (int p = 0; p < 4; ++p) {
    const int pix = pixbase + pg * 4 + p;
    const int i = pix >> 5, j = pix & 31;
    const size_t base = (((size_t)b * 3 + c) * 256 + i * 8 + 7 - ki) * 256 + j * 8;
#pragma unroll
    for (int kj = 0; kj < 8; ++kj) out[base + 7 - kj] = acc[p][kj] + bias;
  }
}

extern "C" void kernel_launch(void* const* d_in, const int* in_sizes, int n_in,
                              void* d_out, int out_size, void* d_ws, size_t ws_size,
                              hipStream_t stream) {
  const float* x     = (const float*)d_in[0];
  const float* enc_w = (const float*)d_in[1];
  const float* enc_b = (const float*)d_in[2];
  const float* dec_w = (const float*)d_in[3];
  const float* dec_b = (const float*)d_in[4];
  const float* emb_w = (const float*)d_in[5];
  float* out = (float*)d_out;
  float* z2 = (float*)d_ws;          // 32768 floats
  float* w2 = z2 + 32768;            // 512 floats

  k_encode<<<dim3(512, 8), 256, 0, stream>>>(x, enc_w, enc_b, out);
  k_norms<<<130, 256, 0, stream>>>(emb_w, out, z2, w2);
  k_dist<<<1024, 256, 0, stream>>>(emb_w, z2, w2, out);
  k_decode<<<dim3(256, 3), 256, 0, stream>>>(dec_w, dec_b, out);
}

// Round 2
// 434.011 us; speedup vs baseline: 1.0493x; 1.0493x over previous
//
#include <hip/hip_runtime.h>
#include <cfloat>

#define PIXB 1024
static const size_t OFF_Z = 6291456;   // recon = 32*3*256*256
static const size_t OFF_E = 23068672;  // OFF_Z + 32*512*32*32
static const size_t OFF_A = 39845888;  // OFF_E + 32*512*32*32

typedef __attribute__((address_space(1))) const unsigned int cg_u32;
typedef __attribute__((address_space(3))) unsigned int l_u32;

// ---------------- encode: z_e = conv(x) + b, as GEMM 512x192 @ 192x32768 ----
// plus 2 extra blocks (blockIdx.y==8) computing w2[k] = sum_d W[d,k]^2
__global__ __launch_bounds__(256) void k_encode(const float* __restrict__ x,
                                                const float* __restrict__ ew,
                                                const float* __restrict__ eb,
                                                const float* __restrict__ emb,
                                                float* __restrict__ w2,
                                                float* __restrict__ out) {
  if (blockIdx.y == 8) {
    if (blockIdx.x < 2) {
      const int k = blockIdx.x * 256 + threadIdx.x;
      float acc = 0.f;
      for (int d = 0; d < 512; ++d) { const float v = emb[(size_t)d * 512 + k]; acc = fmaf(v, v, acc); }
      w2[k] = acc;
    }
    return;
  }
  __shared__ __align__(16) float Ps[16][68];
  __shared__ __align__(16) float Ws[16][68];
  const int n0 = blockIdx.x * 64;
  const int b = n0 / PIXB;
  const int pixbase = n0 % PIXB;
  const int i0 = pixbase >> 5;
  const int c0 = blockIdx.y * 64;
  const int t = threadIdx.x;
  const int tx = t & 15, ty = t >> 4;
  float acc[4][4];
#pragma unroll
  for (int m = 0; m < 4; ++m)
#pragma unroll
    for (int p = 0; p < 4; ++p) acc[m][p] = 0.f;

  const int jj = t >> 3, kjj = t & 7;
  for (int kc = 0; kc < 12; ++kc) {
    const int ci = kc >> 2, kip = kc & 3;
#pragma unroll
    for (int rr = 0; rr < 4; ++rr) {
      const int di = rr >> 1, dki = rr & 1;
      const int row = (i0 + di) * 8 + kip * 2 + dki;
      const float v = x[(((size_t)b * 3 + ci) * 256 + row) * 256 + t];
      Ps[dki * 8 + kjj][di * 32 + jj] = v;
    }
    const int k0 = kc * 16;
#pragma unroll
    for (int ii = 0; ii < 4; ++ii) {
      const int idx = t + ii * 256;
      const int cc = idx >> 4, kk = idx & 15;
      Ws[kk][cc] = ew[(size_t)(c0 + cc) * 192 + k0 + kk];
    }
    __syncthreads();
#pragma unroll
    for (int kk = 0; kk < 16; ++kk) {
      const float4 av = *reinterpret_cast<const float4*>(&Ws[kk][ty * 4]);
      const float4 bv = *reinterpret_cast<const float4*>(&Ps[kk][tx * 4]);
      const float a[4] = {av.x, av.y, av.z, av.w};
      const float bb[4] = {bv.x, bv.y, bv.z, bv.w};
#pragma unroll
      for (int m = 0; m < 4; ++m)
#pragma unroll
        for (int p = 0; p < 4; ++p) acc[m][p] = fmaf(a[m], bb[p], acc[m][p]);
    }
    __syncthreads();
  }
#pragma unroll
  for (int m = 0; m < 4; ++m) {
    const int c = c0 + ty * 4 + m;
    const float bias = eb[c];
    float4 v;
    v.x = acc[m][0] + bias; v.y = acc[m][1] + bias;
    v.z = acc[m][2] + bias; v.w = acc[m][3] + bias;
    *reinterpret_cast<float4*>(&out[OFF_Z + ((size_t)b * 512 + c) * 1024 + pixbase + tx * 4]) = v;
  }
}

// -------- distance + argmin + gather: per block 32 pixels x all 512 codes ----
// 8x8 microtile, global_load_lds staging, fused z2 (distributed owners)
__global__ __launch_bounds__(256) void k_dist(const float* __restrict__ Wc,
                                              const float* __restrict__ w2ws,
                                              float* out) {
  __shared__ __align__(16) float S[16 * 512];      // W chunk [16][512] (32KB), reused for reductions
  __shared__ __align__(16) float Zs[16 * 32 + 64]; // Z chunk [16][32] + scratch
  const int t = threadIdx.x;
  const int tx = t & 3;          // pixel octet: pixels tx*8 .. tx*8+7
  const int ty = t >> 2;         // code quad 0..63: codes ty*4..+3 and 256+ty*4..+3
  const int w  = t >> 6;         // wave id
  const int lane = t & 63;
  const int n0 = blockIdx.x * 32;
  const int b = n0 >> 10;
  const int pixbase = n0 & 1023;

  float acc[8][8];
#pragma unroll
  for (int p = 0; p < 8; ++p)
#pragma unroll
    for (int c = 0; c < 8; ++c) acc[p][c] = 0.f;
  float z2part[8];
#pragma unroll
  for (int p = 0; p < 8; ++p) z2part[p] = 0.f;

  // per-lane global source for z staging (waves 0,1 only): 8 d-rows x 32 pix per wave
  const float* zsrc = out + OFF_Z + ((size_t)(b * 512 + w * 8 + (lane >> 3))) * 1024 + pixbase + (lane & 7) * 4;

  for (int ch = 0; ch < 32; ++ch) {
    const int dbase = ch * 16;
    // stage W: 16 rows x 512 codes; 32 1KB-segments, 8 per wave
#pragma unroll
    for (int i = 0; i < 8; ++i) {
      const int r = w * 4 + (i >> 1);
      const int half = i & 1;
      const float* src = Wc + ((size_t)(dbase + r)) * 512 + half * 256 + lane * 4;
      __builtin_amdgcn_global_load_lds((cg_u32*)src, (l_u32*)&S[r * 512 + half * 256], 16, 0, 0);
    }
    // stage z: 16 rows x 32 pix = 2KB, waves 0,1
    if (w < 2) {
      const float* src = zsrc + (size_t)dbase * 1024;
      __builtin_amdgcn_global_load_lds((cg_u32*)src, (l_u32*)&Zs[w * 256], 16, 0, 0);
    }
    __syncthreads();
    const int cHi = ch >> 3;
#pragma unroll
    for (int dd = 0; dd < 16; ++dd) {
      const float4 zv0 = *reinterpret_cast<const float4*>(&Zs[dd * 32 + tx * 8]);
      const float4 zv1 = *reinterpret_cast<const float4*>(&Zs[dd * 32 + tx * 8 + 4]);
      const float4 wv0 = *reinterpret_cast<const float4*>(&S[dd * 512 + ty * 4]);
      const float4 wv1 = *reinterpret_cast<const float4*>(&S[dd * 512 + 256 + ty * 4]);
      const float z[8]  = {zv0.x, zv0.y, zv0.z, zv0.w, zv1.x, zv1.y, zv1.z, zv1.w};
      const float wv[8] = {wv0.x, wv0.y, wv0.z, wv0.w, wv1.x, wv1.y, wv1.z, wv1.w};
#pragma unroll
      for (int p = 0; p < 8; ++p)
#pragma unroll
        for (int c = 0; c < 8; ++c) acc[p][c] = fmaf(z[p], wv[c], acc[p][c]);
      if (ty == dd * 4 + cHi) {   // distributed z2 ownership: d = ch*16+dd
#pragma unroll
        for (int p = 0; p < 8; ++p) z2part[p] = fmaf(z[p], z[p], z2part[p]);
      }
    }
    __syncthreads();
  }

  // ---- z2 reduce over the 64 ty owners (deterministic order) ----
#pragma unroll
  for (int p = 0; p < 8; ++p) S[4096 + ty * 32 + tx * 8 + p] = z2part[p];
  __syncthreads();
  if (t < 32) {
    float s = 0.f;
    for (int y = 0; y < 64; ++y) s += S[4096 + y * 32 + t];
    Zs[512 + t] = s;
  }
  __syncthreads();
  float z2r[8];
#pragma unroll
  for (int p = 0; p < 8; ++p) z2r[p] = Zs[512 + tx * 8 + p];

  // ---- d2 + per-thread argmin (ref rounding: (z2 - 2*zw) + w2) ----
  float bestv[8]; int besti[8];
#pragma unroll
  for (int p = 0; p < 8; ++p) { bestv[p] = FLT_MAX; besti[p] = 0x7fffffff; }
#pragma unroll
  for (int c = 0; c < 8; ++c) {
    const int code = (c < 4) ? (ty * 4 + c) : (256 + ty * 4 + (c - 4));
    const float w2v = w2ws[code];
#pragma unroll
    for (int p = 0; p < 8; ++p) {
      const float s1 = z2r[p] - 2.0f * acc[p][c];
      const float d2v = s1 + w2v;
      if (d2v < bestv[p] || (d2v == bestv[p] && code < besti[p])) { bestv[p] = d2v; besti[p] = code; }
    }
  }

  // ---- cross-thread argmin reduce (64 ty per pixel), first-index tie-break ----
  int* ri = reinterpret_cast<int*>(&S[2048]);
#pragma unroll
  for (int p = 0; p < 8; ++p) { S[ty * 32 + tx * 8 + p] = bestv[p]; ri[ty * 32 + tx * 8 + p] = besti[p]; }
  __syncthreads();
  if (t < 32) {
    float bv = S[t]; int bi = ri[t];
    for (int y = 1; y < 64; ++y) {
      const float v = S[y * 32 + t]; const int ii = ri[y * 32 + t];
      if (v < bv || (v == bv && ii < bi)) { bv = v; bi = ii; }
    }
    out[OFF_A + n0 + t] = (float)bi;
    reinterpret_cast<int*>(&Zs[544])[t] = bi;
  }
  __syncthreads();

  // ---- gather emb ----
  const int pix = t & 31;
  const int kidx = reinterpret_cast<int*>(&Zs[544])[pix];
  for (int d = t >> 5; d < 512; d += 8)
    out[OFF_E + ((size_t)(b * 512 + d)) * 1024 + pixbase + pix] = Wc[(size_t)d * 512 + kidx];
}

// ---------------- decode: conv_transpose (kernel spatially FLIPPED) ---------
__global__ __launch_bounds__(256) void k_decode(const float* __restrict__ dw,
                                                const float* __restrict__ db,
                                                float* out) {
  __shared__ __align__(16) float Qs[32][132];
  __shared__ __align__(16) float Ws3[32][68];
  const int n0 = blockIdx.x * 128;
  const int b = n0 / PIXB, pixbase = n0 % PIXB;
  const int mt = blockIdx.y;
  const int t = threadIdx.x;
  const int pg = t & 31, ck = t >> 5;
  float acc[4][8];
#pragma unroll
  for (int p = 0; p < 4; ++p)
#pragma unroll
    for (int k = 0; k < 8; ++k) acc[p][k] = 0.f;
  for (int dc = 0; dc < 16; ++dc) {
#pragma unroll
    for (int ii = 0; ii < 4; ++ii) {
      const int id = t + ii * 256;
      const int dd = id >> 5, p4 = id & 31;
      *reinterpret_cast<float4*>(&Qs[dd][p4 * 4]) =
        *reinterpret_cast<const float4*>(&out[OFF_E + ((size_t)b * 512 + dc * 32 + dd) * 1024 + pixbase + p4 * 4]);
    }
#pragma unroll
    for (int ii = 0; ii < 2; ++ii) {
      const int id = t + ii * 256;
      const int dd = id >> 4, m4 = id & 15;
      *reinterpret_cast<float4*>(&Ws3[dd][m4 * 4]) =
        *reinterpret_cast<const float4*>(&dw[(size_t)(dc * 32 + dd) * 192 + mt * 64 + m4 * 4]);
    }
    __syncthreads();
#pragma unroll
    for (int dd = 0; dd < 32; ++dd) {
      const float4 qv = *reinterpret_cast<const float4*>(&Qs[dd][pg * 4]);
      const float4 wa = *reinterpret_cast<const float4*>(&Ws3[dd][ck * 8]);
      const float4 wb = *reinterpret_cast<const float4*>(&Ws3[dd][ck * 8 + 4]);
      const float q[4] = {qv.x, qv.y, qv.z, qv.w};
      const float w[8] = {wa.x, wa.y, wa.z, wa.w, wb.x, wb.y, wb.z, wb.w};
#pragma unroll
      for (int p = 0; p < 4; ++p)
#pragma unroll
        for (int k = 0; k < 8; ++k) acc[p][k] = fmaf(q[p], w[k], acc[p][k]);
    }
    __syncthreads();
  }
  const int ckg = mt * 8 + ck;
  const int c = ckg >> 3, ki = ckg & 7;
  const float bias = db[c];
#pragma unroll
  for (int p = 0; p < 4; ++p) {
    const int pix = pixbase + pg * 4 + p;
    const int i = pix >> 5, j = pix & 31;
    const size_t base = (((size_t)b * 3 + c) * 256 + i * 8 + 7 - ki) * 256 + j * 8;
#pragma unroll
    for (int kj = 0; kj < 8; ++kj) out[base + 7 - kj] = acc[p][kj] + bias;
  }
}

extern "C" void kernel_launch(void* const* d_in, const int* in_sizes, int n_in,
                              void* d_out, int out_size, void* d_ws, size_t ws_size,
                              hipStream_t stream) {
  const float* x     = (const float*)d_in[0];
  const float* enc_w = (const float*)d_in[1];
  const float* enc_b = (const float*)d_in[2];
  const float* dec_w = (const float*)d_in[3];
  const float* dec_b = (const float*)d_in[4];
  const float* emb_w = (const float*)d_in[5];
  float* out = (float*)d_out;
  float* w2 = (float*)d_ws;          // 512 floats

  k_encode<<<dim3(512, 9), 256, 0, stream>>>(x, enc_w, enc_b, emb_w, w2, out);
  k_dist<<<1024, 256, 0, stream>>>(emb_w, w2, out);
  k_decode<<<dim3(256, 3), 256, 0, stream>>>(dec_w, dec_b, out);
}